// Round 1
// 1466.696 us; speedup vs baseline: 1.0100x; 1.0100x over previous
//
#include <hip/hip_runtime.h>
#include <math.h>

typedef __attribute__((ext_vector_type(4))) float f32x4;
typedef __attribute__((ext_vector_type(8))) short s16x8;

__device__ __forceinline__ unsigned rotl32(unsigned x, int r) {
    return (x << r) | (x >> (32 - r));
}
__device__ __forceinline__ unsigned short f2bf(float x) {
    unsigned u = __float_as_uint(x);
    unsigned r = (u + 0x7FFFu + ((u >> 16) & 1u)) >> 16;   // RNE
    return (unsigned short)r;
}
__device__ __forceinline__ float b2f(unsigned short b) {
    return __uint_as_float((unsigned)b << 16);
}
__device__ __forceinline__ void async16(const unsigned short* g, unsigned short* l) {
    __builtin_amdgcn_global_load_lds(
        (const __attribute__((address_space(1))) void*)g,
        (__attribute__((address_space(3))) void*)l, 16, 0, 0);
}

// XLA f32 erfinv (Giles polynomial)
__device__ __forceinline__ float bits_to_normal(unsigned bits) {
    float f = __uint_as_float((bits >> 9) | 0x3F800000u) - 1.0f;
    const float lo = -0.99999994f;
    float u = f * 2.0f + lo;
    u = fmaxf(lo, u);
    float w = -log1pf(-u * u);
    float p;
    if (w < 5.0f) {
        w -= 2.5f;
        p = 2.81022636e-08f;
        p = fmaf(p, w, 3.43273939e-07f);
        p = fmaf(p, w, -3.5233877e-06f);
        p = fmaf(p, w, -4.39150654e-06f);
        p = fmaf(p, w, 0.00021858087f);
        p = fmaf(p, w, -0.00125372503f);
        p = fmaf(p, w, -0.00417768164f);
        p = fmaf(p, w, 0.246640727f);
        p = fmaf(p, w, 1.50140941f);
    } else {
        w = sqrtf(w) - 3.0f;
        p = -0.000200214257f;
        p = fmaf(p, w, 0.000100950558f);
        p = fmaf(p, w, 0.00134934322f);
        p = fmaf(p, w, -0.00367342844f);
        p = fmaf(p, w, 0.00573950773f);
        p = fmaf(p, w, -0.0076224613f);
        p = fmaf(p, w, 0.00943887047f);
        p = fmaf(p, w, 1.00167406f);
        p = fmaf(p, w, 2.83297682f);
    }
    return 1.41421356237f * (p * u);
}

// slots = mu + |sigma| * threefry_normal(key=(0,1)), partitionable scheme.
__global__ __launch_bounds__(256)
void k_init_slots(const float* __restrict__ mu, const float* __restrict__ sigma,
                  float* __restrict__ slots, unsigned short* __restrict__ slotsb) {
    unsigned e = blockIdx.x * 256u + threadIdx.x;
    const unsigned ks0 = 0u, ks1 = 1u, ks2 = 0x1BD11BDBu;
    unsigned x0 = 0u + ks0;
    unsigned x1 = e + ks1;
#define TF_RND(r) { x0 += x1; x1 = rotl32(x1, r); x1 ^= x0; }
    TF_RND(13) TF_RND(15) TF_RND(26) TF_RND(6)   x0 += ks1; x1 += ks2 + 1u;
    TF_RND(17) TF_RND(29) TF_RND(16) TF_RND(24)  x0 += ks2; x1 += ks0 + 2u;
    TF_RND(13) TF_RND(15) TF_RND(26) TF_RND(6)   x0 += ks0; x1 += ks1 + 3u;
    TF_RND(17) TF_RND(29) TF_RND(16) TF_RND(24)  x0 += ks1; x1 += ks2 + 4u;
    TF_RND(13) TF_RND(15) TF_RND(26) TF_RND(6)   x0 += ks2; x1 += ks0 + 5u;
#undef TF_RND
    unsigned bits = x0 ^ x1;
    int d0 = (int)(e & 511u);
    float v = mu[d0] + fabsf(sigma[d0]) * bits_to_normal(bits);
    slots[e] = v;
    slotsb[e] = f2bf(v);
}

// flat f32 -> bf16 cast, 4 elems/thread
__global__ __launch_bounds__(256)
void k_cast(const float* __restrict__ s, unsigned short* __restrict__ d, int n4) {
    int i = blockIdx.x * 256 + threadIdx.x;
    if (i < n4) {
        float4 v = ((const float4*)s)[i];
        ((ushort4*)d)[i] = make_ushort4(f2bf(v.x), f2bf(v.y), f2bf(v.z), f2bf(v.w));
    }
}

// x [128][1024][512] f32 (b,j,d) -> xT [128][512][1024] bf16 (b,d,j)
__global__ __launch_bounds__(256)
void k_transpose_cast(const float* __restrict__ x, unsigned short* __restrict__ xT) {
    __shared__ float t[32][33];
    int b = blockIdx.z;
    int j0 = blockIdx.x * 32;
    int d0 = blockIdx.y * 32;
    int tx = threadIdx.x & 31, ty = threadIdx.x >> 5;   // ty 0..7
    const float* xp = x + ((long long)b * 1024 + j0) * 512 + d0;
#pragma unroll
    for (int q = 0; q < 4; q++) {
        int j = ty + q * 8;
        t[j][tx] = xp[(long long)j * 512 + tx];
    }
    __syncthreads();
    unsigned short* op = xT + ((long long)b * 512 + d0) * 1024 + j0;
#pragma unroll
    for (int q = 0; q < 4; q++) {
        int d = ty + q * 8;
        op[(long long)d * 1024 + tx] = f2bf(t[tx][d]);
    }
}

// C[m,n] = bf16( alpha * sum_k A[m,k]*B[n,k] (+ bias[n]) )
// A: f32 (A_F32, staged w/ in-kernel cast) or bf16 (global_load_lds x16B).
// B: bf16 [N x K] row-major (NT). 128x128 tile, BK=32, 4 waves, 16x16x32 MFMA.
// XSWZ: 1-D grid, XCD-aware decode — each XCD (L%8) owns a contiguous range of
// M-panels and the N-blocks of one panel are adjacent in that XCD's queue, so
// the A-panel is fetched from HBM once and re-read from that XCD's L2.
// Requires gridDim.x % 32 == 0, N/128 == 4.
template<bool A_F32, bool HAS_BIAS, bool XSWZ = false>
__global__ __launch_bounds__(256)
void k_mfma_nt(const void* __restrict__ Araw, long long sA,
               const unsigned short* __restrict__ B, long long sB,
               unsigned short* __restrict__ C, long long sC,
               const float* __restrict__ bias,
               int M, int N, int K, float alpha) {
    __shared__ __align__(16) unsigned short As[128 * 32];
    __shared__ __align__(16) unsigned short Bs[128 * 32];
    const int tid = threadIdx.x;
    const unsigned short* Ab = (const unsigned short*)Araw + (long long)blockIdx.z * sA;
    const float* Af = (const float*)Araw + (long long)blockIdx.z * sA;
    const unsigned short* Bb = B + (long long)blockIdx.z * sB;
    C += (long long)blockIdx.z * sC;

    int nb, mb;
    if (XSWZ) {
        unsigned L = blockIdx.x;
        unsigned x = L & 7u;               // XCD (round-robin dispatch)
        unsigned j = L >> 3u;              // position within this XCD's queue
        unsigned panels = gridDim.x >> 5u; // M-panels per XCD (grid/8/4)
        mb = (int)(x * panels + (j >> 2u));
        nb = (int)(j & 3u);
    } else {
        nb = blockIdx.x;
        mb = blockIdx.y;
    }
    const int n0 = nb * 128;
    const int m0 = mb * 128;

    const int lane = tid & 63;
    const int wave = tid >> 6;
    const int wm = (wave >> 1) * 64;
    const int wn = (wave & 1) * 64;
    const int lrow = lane & 15;
    const int lquad = lane >> 4;

    f32x4 acc[4][4];
#pragma unroll
    for (int i = 0; i < 4; i++)
#pragma unroll
        for (int j = 0; j < 4; j++) acc[i][j] = (f32x4)0.0f;

    // staging coords
    const int arow_s = tid >> 1;                 // A_F32: row, 2 thr/row
    const int akh_s = (tid & 1) * 16;            // A_F32: k sub-offset
    int arowg_s = m0 + arow_s; if (arowg_s >= M) arowg_s = M - 1;

    for (int k0 = 0; k0 < K; k0 += 32) {
        float4 f0, f1, f2, f3;
        if (A_F32) {
            const float* ap = Af + (long long)arowg_s * K + k0 + akh_s;
            f0 = *(const float4*)(ap);
            f1 = *(const float4*)(ap + 4);
            f2 = *(const float4*)(ap + 8);
            f3 = *(const float4*)(ap + 12);
        }
        __syncthreads();   // LDS safe to overwrite
        if (A_F32) {
            s16x8 p0, p1;
            p0[0] = (short)f2bf(f0.x); p0[1] = (short)f2bf(f0.y);
            p0[2] = (short)f2bf(f0.z); p0[3] = (short)f2bf(f0.w);
            p0[4] = (short)f2bf(f1.x); p0[5] = (short)f2bf(f1.y);
            p0[6] = (short)f2bf(f1.z); p0[7] = (short)f2bf(f1.w);
            p1[0] = (short)f2bf(f2.x); p1[1] = (short)f2bf(f2.y);
            p1[2] = (short)f2bf(f2.z); p1[3] = (short)f2bf(f2.w);
            p1[4] = (short)f2bf(f3.x); p1[5] = (short)f2bf(f3.y);
            p1[6] = (short)f2bf(f3.z); p1[7] = (short)f2bf(f3.w);
            *(s16x8*)&As[arow_s * 32 + akh_s] = p0;
            *(s16x8*)&As[arow_s * 32 + akh_s + 8] = p1;
        } else {
#pragma unroll
            for (int p = 0; p < 2; p++) {
                int c = p * 256 + tid;
                int row = c >> 2;
                int kc = (c & 3) * 8;
                int rowg = m0 + row; if (rowg >= M) rowg = M - 1;
                async16(Ab + (long long)rowg * K + k0 + kc,
                        &As[(p * 256 + (tid & ~63)) * 8]);
            }
        }
#pragma unroll
        for (int p = 0; p < 2; p++) {
            int c = p * 256 + tid;
            int row = c >> 2;
            int kc = (c & 3) * 8;
            async16(Bb + (long long)(n0 + row) * K + k0 + kc,
                    &Bs[(p * 256 + (tid & ~63)) * 8]);
        }
        __syncthreads();   // drains vmcnt (global_load_lds) + lgkmcnt

        s16x8 afr[4], bfr[4];
#pragma unroll
        for (int i = 0; i < 4; i++)
            afr[i] = *(const s16x8*)&As[(wm + i * 16 + lrow) * 32 + lquad * 8];
#pragma unroll
        for (int j = 0; j < 4; j++)
            bfr[j] = *(const s16x8*)&Bs[(wn + j * 16 + lrow) * 32 + lquad * 8];
#pragma unroll
        for (int i = 0; i < 4; i++)
#pragma unroll
            for (int j = 0; j < 4; j++)
                acc[i][j] = __builtin_amdgcn_mfma_f32_16x16x32_bf16(
                    afr[i], bfr[j], acc[i][j], 0, 0, 0);
    }

#pragma unroll
    for (int i = 0; i < 4; i++) {
#pragma unroll
        for (int r = 0; r < 4; r++) {
            int grow = m0 + wm + i * 16 + lquad * 4 + r;
            if (grow < M) {
#pragma unroll
                for (int j = 0; j < 4; j++) {
                    int gcol = n0 + wn + j * 16 + lrow;
                    float v = acc[i][j][r] * alpha;
                    if (HAS_BIAS) v += bias[gcol];
                    C[(long long)grow * N + gcol] = f2bf(v);
                }
            }
        }
    }
}

// in-place row softmax over 1024 bf16, one 256-thread block per row
__global__ __launch_bounds__(256)
void k_softmax_bf(unsigned short* __restrict__ attn) {
    __shared__ float red[8];
    unsigned short* p = attn + (long long)blockIdx.x * 1024;
    ushort4 v = ((const ushort4*)p)[threadIdx.x];
    float a0 = b2f(v.x), a1 = b2f(v.y), a2 = b2f(v.z), a3 = b2f(v.w);
    float mx = fmaxf(fmaxf(a0, a1), fmaxf(a2, a3));
#pragma unroll
    for (int off = 32; off; off >>= 1) mx = fmaxf(mx, __shfl_down(mx, off));
    int wid = threadIdx.x >> 6, lane = threadIdx.x & 63;
    if (lane == 0) red[wid] = mx;
    __syncthreads();
    mx = fmaxf(fmaxf(red[0], red[1]), fmaxf(red[2], red[3]));
    float e0 = expf(a0 - mx), e1 = expf(a1 - mx);
    float e2 = expf(a2 - mx), e3 = expf(a3 - mx);
    float s = (e0 + e1) + (e2 + e3);
#pragma unroll
    for (int off = 32; off; off >>= 1) s += __shfl_down(s, off);
    if (lane == 0) red[4 + wid] = s;
    __syncthreads();
    float inv = 1.0f / ((red[4] + red[5]) + (red[6] + red[7]));
    ((ushort4*)p)[threadIdx.x] =
        make_ushort4(f2bf(e0 * inv), f2bf(e1 * inv), f2bf(e2 * inv), f2bf(e3 * inv));
}

// GRU pointwise from bf16 gate pre-activations; slots updated in place (f32+bf16)
__global__ __launch_bounds__(256)
void k_gru_pw(const unsigned short* __restrict__ gi, const unsigned short* __restrict__ gh,
              const float* __restrict__ bih, const float* __restrict__ bhh,
              float* __restrict__ slots, unsigned short* __restrict__ slotsb) {
    long long idx = (long long)blockIdx.x * 256 + threadIdx.x;
    int m = (int)(idx >> 9);
    int c = (int)(idx & 511);
    const unsigned short* gim = gi + (long long)m * 1536;
    const unsigned short* ghm = gh + (long long)m * 1536;
    float r = 1.0f / (1.0f + expf(-(b2f(gim[c]) + b2f(ghm[c]) + bih[c] + bhh[c])));
    float z = 1.0f / (1.0f + expf(-(b2f(gim[512 + c]) + b2f(ghm[512 + c])
                                    + bih[512 + c] + bhh[512 + c])));
    float hn = b2f(ghm[1024 + c]) + bhh[1024 + c];
    float nn = tanhf(b2f(gim[1024 + c]) + bih[1024 + c] + r * hn);
    float hp = slots[idx];
    float h = (1.0f - z) * nn + z * hp;
    slots[idx] = h;
    slotsb[idx] = f2bf(h);
}

// out[row] = sum_d updb[row, d];  out[12800] = 1/1024 (slot_loss, exact)
__global__ __launch_bounds__(128)
void k_out(const unsigned short* __restrict__ updb, float* __restrict__ out) {
    __shared__ float r2[2];
    const unsigned short* p = updb + (long long)blockIdx.x * 512;
    ushort4 v = ((const ushort4*)p)[threadIdx.x];
    float s = (b2f(v.x) + b2f(v.y)) + (b2f(v.z) + b2f(v.w));
#pragma unroll
    for (int off = 32; off; off >>= 1) s += __shfl_down(s, off);
    if ((threadIdx.x & 63) == 0) r2[threadIdx.x >> 6] = s;
    __syncthreads();
    if (threadIdx.x == 0) {
        out[blockIdx.x] = r2[0] + r2[1];
        if (blockIdx.x == 0) out[12800] = 0.0009765625f;
    }
}

extern "C" void kernel_launch(void* const* d_in, const int* in_sizes, int n_in,
                              void* d_out, int out_size, void* d_ws, size_t ws_size,
                              hipStream_t stream) {
    const float* inputs   = (const float*)d_in[0];
    const float* inputs_x = (const float*)d_in[1];
    const float* mu       = (const float*)d_in[2];
    const float* sigma    = (const float*)d_in[3];
    const float* to_q_w   = (const float*)d_in[4];
    const float* to_q_b   = (const float*)d_in[5];
    const float* to_k_w   = (const float*)d_in[6];
    const float* to_k_b   = (const float*)d_in[7];
    const float* w_ih     = (const float*)d_in[8];
    const float* w_hh     = (const float*)d_in[9];
    const float* b_ih     = (const float*)d_in[10];
    const float* b_hh     = (const float*)d_in[11];
    float* out = (float*)d_out;

    // ws layout (bytes), total 403,701,760 (< 425.7 MB proven available):
    char* base = (char*)d_ws;
    unsigned short* k_bf   = (unsigned short*)(base);                 // 134,217,728
    unsigned short* xT     = (unsigned short*)(base + 134217728ll);   // 134,217,728
    float*          slots  = (float*)        (base + 268435456ll);    //  26,214,400
    unsigned short* slotsb = (unsigned short*)(base + 294649856ll);   //  13,107,200
    unsigned short* updb   = (unsigned short*)(base + 307757056ll);   //  13,107,200
    char* regionA          = base + 320864256ll;                      //  39,321,600 (q | gi)
    char* regionB          = base + 360185856ll;                      //  39,321,600 (attn | gh)
    unsigned short* Wk_bf  = (unsigned short*)(base + 399507456ll);   //     524,288
    unsigned short* Wq_bf  = (unsigned short*)(base + 400031744ll);   //     524,288
    unsigned short* Wih_bf = (unsigned short*)(base + 400556032ll);   //   1,572,864
    unsigned short* Whh_bf = (unsigned short*)(base + 402128896ll);   //   1,572,864
    unsigned short* q_bf   = (unsigned short*)regionA;
    unsigned short* gi_bf  = (unsigned short*)regionA;
    unsigned short* attnb  = (unsigned short*)regionB;
    unsigned short* gh_bf  = (unsigned short*)regionB;

    k_init_slots<<<25600, 256, 0, stream>>>(mu, sigma, slots, slotsb);
    k_cast<<<256, 256, 0, stream>>>(to_k_w, Wk_bf, 65536);
    k_cast<<<256, 256, 0, stream>>>(to_q_w, Wq_bf, 65536);
    k_cast<<<768, 256, 0, stream>>>(w_ih, Wih_bf, 196608);
    k_cast<<<768, 256, 0, stream>>>(w_hh, Whh_bf, 196608);
    k_transpose_cast<<<dim3(32, 16, 128), 256, 0, stream>>>(inputs_x, xT);

    // k = inputs @ Wk.T + bk : [131072 x 512], A fp32 staged.
    // XCD-swizzled 1-D grid: 4096 blocks = 8 XCDs x 128 M-panels x 4 N-blocks.
    k_mfma_nt<true, true, true><<<dim3(4096, 1, 1), 256, 0, stream>>>(
        inputs, 0, Wk_bf, 0, k_bf, 0, to_k_b, 131072, 512, 512, 1.0f);

    const float scale = 0.044194173824159216f;   // 512^-0.5
    for (int it = 0; it < 3; ++it) {
        // q = slots @ Wq.T + bq : [12800 x 512]
        k_mfma_nt<false, true><<<dim3(4, 100, 1), 256, 0, stream>>>(
            slotsb, 0, Wq_bf, 0, q_bf, 0, to_q_b, 12800, 512, 512, 1.0f);
        // dots = scale * q @ k^T : 128 x [100 x 1024]
        k_mfma_nt<false, false><<<dim3(8, 1, 128), 256, 0, stream>>>(
            q_bf, 51200, k_bf, 524288, attnb, 102400, nullptr, 100, 1024, 512, scale);
        k_softmax_bf<<<12800, 256, 0, stream>>>(attnb);
        // updates = (attn @ x) / 512 : 128 x [100 x 512] (x pre-transposed)
        k_mfma_nt<false, false><<<dim3(4, 1, 128), 256, 0, stream>>>(
            attnb, 102400, xT, 524288, updb, 51200, nullptr, 100, 512, 1024, 0.001953125f);
        // gi = upd @ Wih.T ; gh = slots @ Whh.T : [12800 x 1536]
        k_mfma_nt<false, false><<<dim3(12, 100, 1), 256, 0, stream>>>(
            updb, 0, Wih_bf, 0, gi_bf, 0, nullptr, 12800, 1536, 512, 1.0f);
        k_mfma_nt<false, false><<<dim3(12, 100, 1), 256, 0, stream>>>(
            slotsb, 0, Whh_bf, 0, gh_bf, 0, nullptr, 12800, 1536, 512, 1.0f);
        k_gru_pw<<<25600, 256, 0, stream>>>(gi_bf, gh_bf, b_ih, b_hh, slots, slotsb);
    }
    k_out<<<12800, 128, 0, stream>>>(updb, out);
}

// Round 2
// 1447.755 us; speedup vs baseline: 1.0232x; 1.0131x over previous
//
#include <hip/hip_runtime.h>
#include <math.h>

typedef __attribute__((ext_vector_type(4))) float f32x4;
typedef __attribute__((ext_vector_type(8))) short s16x8;

__device__ __forceinline__ unsigned rotl32(unsigned x, int r) {
    return (x << r) | (x >> (32 - r));
}
__device__ __forceinline__ unsigned short f2bf(float x) {
    unsigned u = __float_as_uint(x);
    unsigned r = (u + 0x7FFFu + ((u >> 16) & 1u)) >> 16;   // RNE
    return (unsigned short)r;
}
__device__ __forceinline__ float b2f(unsigned short b) {
    return __uint_as_float((unsigned)b << 16);
}
__device__ __forceinline__ void async16(const unsigned short* g, unsigned short* l) {
    __builtin_amdgcn_global_load_lds(
        (const __attribute__((address_space(1))) void*)g,
        (__attribute__((address_space(3))) void*)l, 16, 0, 0);
}

// XLA f32 erfinv (Giles polynomial)
__device__ __forceinline__ float bits_to_normal(unsigned bits) {
    float f = __uint_as_float((bits >> 9) | 0x3F800000u) - 1.0f;
    const float lo = -0.99999994f;
    float u = f * 2.0f + lo;
    u = fmaxf(lo, u);
    float w = -log1pf(-u * u);
    float p;
    if (w < 5.0f) {
        w -= 2.5f;
        p = 2.81022636e-08f;
        p = fmaf(p, w, 3.43273939e-07f);
        p = fmaf(p, w, -3.5233877e-06f);
        p = fmaf(p, w, -4.39150654e-06f);
        p = fmaf(p, w, 0.00021858087f);
        p = fmaf(p, w, -0.00125372503f);
        p = fmaf(p, w, -0.00417768164f);
        p = fmaf(p, w, 0.246640727f);
        p = fmaf(p, w, 1.50140941f);
    } else {
        w = sqrtf(w) - 3.0f;
        p = -0.000200214257f;
        p = fmaf(p, w, 0.000100950558f);
        p = fmaf(p, w, 0.00134934322f);
        p = fmaf(p, w, -0.00367342844f);
        p = fmaf(p, w, 0.00573950773f);
        p = fmaf(p, w, -0.0076224613f);
        p = fmaf(p, w, 0.00943887047f);
        p = fmaf(p, w, 1.00167406f);
        p = fmaf(p, w, 2.83297682f);
    }
    return 1.41421356237f * (p * u);
}

// slots = mu + |sigma| * threefry_normal(key=(0,1)), partitionable scheme.
__global__ __launch_bounds__(256)
void k_init_slots(const float* __restrict__ mu, const float* __restrict__ sigma,
                  float* __restrict__ slots, unsigned short* __restrict__ slotsb) {
    unsigned e = blockIdx.x * 256u + threadIdx.x;
    const unsigned ks0 = 0u, ks1 = 1u, ks2 = 0x1BD11BDBu;
    unsigned x0 = 0u + ks0;
    unsigned x1 = e + ks1;
#define TF_RND(r) { x0 += x1; x1 = rotl32(x1, r); x1 ^= x0; }
    TF_RND(13) TF_RND(15) TF_RND(26) TF_RND(6)   x0 += ks1; x1 += ks2 + 1u;
    TF_RND(17) TF_RND(29) TF_RND(16) TF_RND(24)  x0 += ks2; x1 += ks0 + 2u;
    TF_RND(13) TF_RND(15) TF_RND(26) TF_RND(6)   x0 += ks0; x1 += ks1 + 3u;
    TF_RND(17) TF_RND(29) TF_RND(16) TF_RND(24)  x0 += ks1; x1 += ks2 + 4u;
    TF_RND(13) TF_RND(15) TF_RND(26) TF_RND(6)   x0 += ks2; x1 += ks0 + 5u;
#undef TF_RND
    unsigned bits = x0 ^ x1;
    int d0 = (int)(e & 511u);
    float v = mu[d0] + fabsf(sigma[d0]) * bits_to_normal(bits);
    slots[e] = v;
    slotsb[e] = f2bf(v);
}

// flat f32 -> bf16 cast, 4 elems/thread
__global__ __launch_bounds__(256)
void k_cast(const float* __restrict__ s, unsigned short* __restrict__ d, int n4) {
    int i = blockIdx.x * 256 + threadIdx.x;
    if (i < n4) {
        float4 v = ((const float4*)s)[i];
        ((ushort4*)d)[i] = make_ushort4(f2bf(v.x), f2bf(v.y), f2bf(v.z), f2bf(v.w));
    }
}

// x [128][1024][512] f32 (b,j,d) -> xT [128][512][1024] bf16 (b,d,j)
__global__ __launch_bounds__(256)
void k_transpose_cast(const float* __restrict__ x, unsigned short* __restrict__ xT) {
    __shared__ float t[32][33];
    int b = blockIdx.z;
    int j0 = blockIdx.x * 32;
    int d0 = blockIdx.y * 32;
    int tx = threadIdx.x & 31, ty = threadIdx.x >> 5;   // ty 0..7
    const float* xp = x + ((long long)b * 1024 + j0) * 512 + d0;
#pragma unroll
    for (int q = 0; q < 4; q++) {
        int j = ty + q * 8;
        t[j][tx] = xp[(long long)j * 512 + tx];
    }
    __syncthreads();
    unsigned short* op = xT + ((long long)b * 512 + d0) * 1024 + j0;
#pragma unroll
    for (int q = 0; q < 4; q++) {
        int d = ty + q * 8;
        op[(long long)d * 1024 + tx] = f2bf(t[tx][d]);
    }
}

// C[m,n] = bf16( alpha * sum_k A[m,k]*B[n,k] (+ bias[n]) )
// A: f32 (A_F32, staged w/ in-kernel cast) or bf16 (global_load_lds x16B).
// B: bf16 [N x K] row-major (NT). 128x128 tile, BK=32, 4 waves, 16x16x32 MFMA.
// 2-PHASE PIPELINE (T3 minimum form): LDS double-buffered; loads for K-step
// t+1 are ISSUED before the MFMA phase of step t and only waited on at the
// single end-of-step __syncthreads (vmcnt drain). A-f32 path: f32 regs loaded
// before MFMA, cast+ds_write after MFMA (latency hidden under MFMA).
// XSWZ: 1-D grid, XCD-aware decode — each XCD (L%8) owns a contiguous range of
// M-panels so the A-panel is HBM-fetched once per XCD L2.
// Requires gridDim.x % 32 == 0, N/128 == 4.
template<bool A_F32, bool HAS_BIAS, bool XSWZ = false>
__global__ __launch_bounds__(256)
void k_mfma_nt(const void* __restrict__ Araw, long long sA,
               const unsigned short* __restrict__ B, long long sB,
               unsigned short* __restrict__ C, long long sC,
               const float* __restrict__ bias,
               int M, int N, int K, float alpha) {
    __shared__ __align__(16) unsigned short As[2][128 * 32];
    __shared__ __align__(16) unsigned short Bs[2][128 * 32];
    const int tid = threadIdx.x;
    const unsigned short* Ab = (const unsigned short*)Araw + (long long)blockIdx.z * sA;
    const float* Af = (const float*)Araw + (long long)blockIdx.z * sA;
    const unsigned short* Bb = B + (long long)blockIdx.z * sB;
    C += (long long)blockIdx.z * sC;

    int nb, mb;
    if (XSWZ) {
        unsigned L = blockIdx.x;
        unsigned x = L & 7u;               // XCD (round-robin dispatch)
        unsigned j = L >> 3u;              // position within this XCD's queue
        unsigned panels = gridDim.x >> 5u; // M-panels per XCD (grid/8/4)
        mb = (int)(x * panels + (j >> 2u));
        nb = (int)(j & 3u);
    } else {
        nb = blockIdx.x;
        mb = blockIdx.y;
    }
    const int n0 = nb * 128;
    const int m0 = mb * 128;

    const int lane = tid & 63;
    const int wave = tid >> 6;
    const int wm = (wave >> 1) * 64;
    const int wn = (wave & 1) * 64;
    const int lrow = lane & 15;
    const int lquad = lane >> 4;

    f32x4 acc[4][4];
#pragma unroll
    for (int i = 0; i < 4; i++)
#pragma unroll
        for (int j = 0; j < 4; j++) acc[i][j] = (f32x4)0.0f;

    // staging coords
    const int arow_s = tid >> 1;                 // A_F32: row, 2 thr/row
    const int akh_s = (tid & 1) * 16;            // A_F32: k sub-offset
    int arowg_s = m0 + arow_s; if (arowg_s >= M) arowg_s = M - 1;

    // async-staging coords (shared by A-bf16 and B paths)
    const int c0_row = tid >> 2;                 // p=0 row
    const int c0_kc = (tid & 3) * 8;
    const int ldsoff0 = (tid & ~63) * 8;         // p=0 LDS elem offset (wave-linear)
    const int ldsoff1 = (256 + (tid & ~63)) * 8; // p=1

    float4 f0, f1, f2, f3;                       // A_F32 prefetch regs

    auto loadAf32 = [&](int k0) {
        const float* ap = Af + (long long)arowg_s * K + k0 + akh_s;
        f0 = *(const float4*)(ap);
        f1 = *(const float4*)(ap + 4);
        f2 = *(const float4*)(ap + 8);
        f3 = *(const float4*)(ap + 12);
    };
    auto castA = [&](unsigned short* dst) {
        s16x8 p0, p1;
        p0[0] = (short)f2bf(f0.x); p0[1] = (short)f2bf(f0.y);
        p0[2] = (short)f2bf(f0.z); p0[3] = (short)f2bf(f0.w);
        p0[4] = (short)f2bf(f1.x); p0[5] = (short)f2bf(f1.y);
        p0[6] = (short)f2bf(f1.z); p0[7] = (short)f2bf(f1.w);
        p1[0] = (short)f2bf(f2.x); p1[1] = (short)f2bf(f2.y);
        p1[2] = (short)f2bf(f2.z); p1[3] = (short)f2bf(f2.w);
        p1[4] = (short)f2bf(f3.x); p1[5] = (short)f2bf(f3.y);
        p1[6] = (short)f2bf(f3.z); p1[7] = (short)f2bf(f3.w);
        *(s16x8*)&dst[arow_s * 32 + akh_s] = p0;
        *(s16x8*)&dst[arow_s * 32 + akh_s + 8] = p1;
    };
    auto stageAasync = [&](int k0, unsigned short* dst) {
        int r0 = m0 + c0_row;       if (r0 >= M) r0 = M - 1;
        int r1 = m0 + 64 + c0_row;  if (r1 >= M) r1 = M - 1;
        async16(Ab + (long long)r0 * K + k0 + c0_kc, &dst[ldsoff0]);
        async16(Ab + (long long)r1 * K + k0 + c0_kc, &dst[ldsoff1]);
    };
    auto stageB = [&](int k0, unsigned short* dst) {
        async16(Bb + (long long)(n0 + c0_row) * K + k0 + c0_kc, &dst[ldsoff0]);
        async16(Bb + (long long)(n0 + 64 + c0_row) * K + k0 + c0_kc, &dst[ldsoff1]);
    };

    const int nt = K >> 5;   // K-steps of 32

    // ---- prologue: stage t=0 into buffer 0 ----
    if (A_F32) {
        loadAf32(0);
        stageB(0, Bs[0]);
        castA(As[0]);
    } else {
        stageAasync(0, As[0]);
        stageB(0, Bs[0]);
    }
    __syncthreads();   // drains vmcnt (async) + lgkmcnt (castA writes)

    int cur = 0;
    for (int t = 0; t < nt; ++t) {
        const int nxt = cur ^ 1;
        const bool more = (t + 1 < nt);
        // ---- issue loads for t+1 (land during MFMA phase) ----
        if (more) {
            const int k1 = (t + 1) << 5;
            if (A_F32) {
                loadAf32(k1);              // f32 -> regs, consumed after MFMA
            } else {
                stageAasync(k1, As[nxt]);
            }
            stageB(k1, Bs[nxt]);
        }
        // ---- compute phase on buffer cur ----
        const unsigned short* Asc = As[cur];
        const unsigned short* Bsc = Bs[cur];
        s16x8 afr[4], bfr[4];
#pragma unroll
        for (int i = 0; i < 4; i++)
            afr[i] = *(const s16x8*)&Asc[(wm + i * 16 + lrow) * 32 + lquad * 8];
#pragma unroll
        for (int j = 0; j < 4; j++)
            bfr[j] = *(const s16x8*)&Bsc[(wn + j * 16 + lrow) * 32 + lquad * 8];
#pragma unroll
        for (int i = 0; i < 4; i++)
#pragma unroll
            for (int j = 0; j < 4; j++)
                acc[i][j] = __builtin_amdgcn_mfma_f32_16x16x32_bf16(
                    afr[i], bfr[j], acc[i][j], 0, 0, 0);
        // ---- finish staging t+1 (A_F32: cast regs -> LDS after MFMA) ----
        if (more && A_F32) castA(As[nxt]);
        __syncthreads();   // single per-step drain: vmcnt (async) + lgkmcnt
        cur = nxt;
    }

#pragma unroll
    for (int i = 0; i < 4; i++) {
#pragma unroll
        for (int r = 0; r < 4; r++) {
            int grow = m0 + wm + i * 16 + lquad * 4 + r;
            if (grow < M) {
#pragma unroll
                for (int j = 0; j < 4; j++) {
                    int gcol = n0 + wn + j * 16 + lrow;
                    float v = acc[i][j][r] * alpha;
                    if (HAS_BIAS) v += bias[gcol];
                    C[(long long)grow * N + gcol] = f2bf(v);
                }
            }
        }
    }
}

// in-place row softmax over 1024 bf16, one 256-thread block per row
__global__ __launch_bounds__(256)
void k_softmax_bf(unsigned short* __restrict__ attn) {
    __shared__ float red[8];
    unsigned short* p = attn + (long long)blockIdx.x * 1024;
    ushort4 v = ((const ushort4*)p)[threadIdx.x];
    float a0 = b2f(v.x), a1 = b2f(v.y), a2 = b2f(v.z), a3 = b2f(v.w);
    float mx = fmaxf(fmaxf(a0, a1), fmaxf(a2, a3));
#pragma unroll
    for (int off = 32; off; off >>= 1) mx = fmaxf(mx, __shfl_down(mx, off));
    int wid = threadIdx.x >> 6, lane = threadIdx.x & 63;
    if (lane == 0) red[wid] = mx;
    __syncthreads();
    mx = fmaxf(fmaxf(red[0], red[1]), fmaxf(red[2], red[3]));
    float e0 = expf(a0 - mx), e1 = expf(a1 - mx);
    float e2 = expf(a2 - mx), e3 = expf(a3 - mx);
    float s = (e0 + e1) + (e2 + e3);
#pragma unroll
    for (int off = 32; off; off >>= 1) s += __shfl_down(s, off);
    if (lane == 0) red[4 + wid] = s;
    __syncthreads();
    float inv = 1.0f / ((red[4] + red[5]) + (red[6] + red[7]));
    ((ushort4*)p)[threadIdx.x] =
        make_ushort4(f2bf(e0 * inv), f2bf(e1 * inv), f2bf(e2 * inv), f2bf(e3 * inv));
}

// GRU pointwise from bf16 gate pre-activations; slots updated in place (f32+bf16)
__global__ __launch_bounds__(256)
void k_gru_pw(const unsigned short* __restrict__ gi, const unsigned short* __restrict__ gh,
              const float* __restrict__ bih, const float* __restrict__ bhh,
              float* __restrict__ slots, unsigned short* __restrict__ slotsb) {
    long long idx = (long long)blockIdx.x * 256 + threadIdx.x;
    int m = (int)(idx >> 9);
    int c = (int)(idx & 511);
    const unsigned short* gim = gi + (long long)m * 1536;
    const unsigned short* ghm = gh + (long long)m * 1536;
    float r = 1.0f / (1.0f + expf(-(b2f(gim[c]) + b2f(ghm[c]) + bih[c] + bhh[c])));
    float z = 1.0f / (1.0f + expf(-(b2f(gim[512 + c]) + b2f(ghm[512 + c])
                                    + bih[512 + c] + bhh[512 + c])));
    float hn = b2f(ghm[1024 + c]) + bhh[1024 + c];
    float nn = tanhf(b2f(gim[1024 + c]) + bih[1024 + c] + r * hn);
    float hp = slots[idx];
    float h = (1.0f - z) * nn + z * hp;
    slots[idx] = h;
    slotsb[idx] = f2bf(h);
}

// out[row] = sum_d updb[row, d];  out[12800] = 1/1024 (slot_loss, exact)
__global__ __launch_bounds__(128)
void k_out(const unsigned short* __restrict__ updb, float* __restrict__ out) {
    __shared__ float r2[2];
    const unsigned short* p = updb + (long long)blockIdx.x * 512;
    ushort4 v = ((const ushort4*)p)[threadIdx.x];
    float s = (b2f(v.x) + b2f(v.y)) + (b2f(v.z) + b2f(v.w));
#pragma unroll
    for (int off = 32; off; off >>= 1) s += __shfl_down(s, off);
    if ((threadIdx.x & 63) == 0) r2[threadIdx.x >> 6] = s;
    __syncthreads();
    if (threadIdx.x == 0) {
        out[blockIdx.x] = r2[0] + r2[1];
        if (blockIdx.x == 0) out[12800] = 0.0009765625f;
    }
}

extern "C" void kernel_launch(void* const* d_in, const int* in_sizes, int n_in,
                              void* d_out, int out_size, void* d_ws, size_t ws_size,
                              hipStream_t stream) {
    const float* inputs   = (const float*)d_in[0];
    const float* inputs_x = (const float*)d_in[1];
    const float* mu       = (const float*)d_in[2];
    const float* sigma    = (const float*)d_in[3];
    const float* to_q_w   = (const float*)d_in[4];
    const float* to_q_b   = (const float*)d_in[5];
    const float* to_k_w   = (const float*)d_in[6];
    const float* to_k_b   = (const float*)d_in[7];
    const float* w_ih     = (const float*)d_in[8];
    const float* w_hh     = (const float*)d_in[9];
    const float* b_ih     = (const float*)d_in[10];
    const float* b_hh     = (const float*)d_in[11];
    float* out = (float*)d_out;

    // ws layout (bytes), total 403,701,760 (< 425.7 MB proven available):
    char* base = (char*)d_ws;
    unsigned short* k_bf   = (unsigned short*)(base);                 // 134,217,728
    unsigned short* xT     = (unsigned short*)(base + 134217728ll);   // 134,217,728
    float*          slots  = (float*)        (base + 268435456ll);    //  26,214,400
    unsigned short* slotsb = (unsigned short*)(base + 294649856ll);   //  13,107,200
    unsigned short* updb   = (unsigned short*)(base + 307757056ll);   //  13,107,200
    char* regionA          = base + 320864256ll;                      //  39,321,600 (q | gi)
    char* regionB          = base + 360185856ll;                      //  39,321,600 (attn | gh)
    unsigned short* Wk_bf  = (unsigned short*)(base + 399507456ll);   //     524,288
    unsigned short* Wq_bf  = (unsigned short*)(base + 400031744ll);   //     524,288
    unsigned short* Wih_bf = (unsigned short*)(base + 400556032ll);   //   1,572,864
    unsigned short* Whh_bf = (unsigned short*)(base + 402128896ll);   //   1,572,864
    unsigned short* q_bf   = (unsigned short*)regionA;
    unsigned short* gi_bf  = (unsigned short*)regionA;
    unsigned short* attnb  = (unsigned short*)regionB;
    unsigned short* gh_bf  = (unsigned short*)regionB;

    k_init_slots<<<25600, 256, 0, stream>>>(mu, sigma, slots, slotsb);
    k_cast<<<256, 256, 0, stream>>>(to_k_w, Wk_bf, 65536);
    k_cast<<<256, 256, 0, stream>>>(to_q_w, Wq_bf, 65536);
    k_cast<<<768, 256, 0, stream>>>(w_ih, Wih_bf, 196608);
    k_cast<<<768, 256, 0, stream>>>(w_hh, Whh_bf, 196608);
    k_transpose_cast<<<dim3(32, 16, 128), 256, 0, stream>>>(inputs_x, xT);

    // k = inputs @ Wk.T + bk : [131072 x 512], A fp32 staged.
    // XCD-swizzled 1-D grid: 4096 blocks = 8 XCDs x 128 M-panels x 4 N-blocks.
    k_mfma_nt<true, true, true><<<dim3(4096, 1, 1), 256, 0, stream>>>(
        inputs, 0, Wk_bf, 0, k_bf, 0, to_k_b, 131072, 512, 512, 1.0f);

    const float scale = 0.044194173824159216f;   // 512^-0.5
    for (int it = 0; it < 3; ++it) {
        // q = slots @ Wq.T + bq : [12800 x 512]
        k_mfma_nt<false, true><<<dim3(4, 100, 1), 256, 0, stream>>>(
            slotsb, 0, Wq_bf, 0, q_bf, 0, to_q_b, 12800, 512, 512, 1.0f);
        // dots = scale * q @ k^T : 128 x [100 x 1024]
        k_mfma_nt<false, false><<<dim3(8, 1, 128), 256, 0, stream>>>(
            q_bf, 51200, k_bf, 524288, attnb, 102400, nullptr, 100, 1024, 512, scale);
        k_softmax_bf<<<12800, 256, 0, stream>>>(attnb);
        // updates = (attn @ x) / 512 : 128 x [100 x 512] (x pre-transposed)
        k_mfma_nt<false, false><<<dim3(4, 1, 128), 256, 0, stream>>>(
            attnb, 102400, xT, 524288, updb, 51200, nullptr, 100, 512, 1024, 0.001953125f);
        // gi = upd @ Wih.T ; gh = slots @ Whh.T : [12800 x 1536]
        k_mfma_nt<false, false><<<dim3(12, 100, 1), 256, 0, stream>>>(
            updb, 0, Wih_bf, 0, gi_bf, 0, nullptr, 12800, 1536, 512, 1.0f);
        k_mfma_nt<false, false><<<dim3(12, 100, 1), 256, 0, stream>>>(
            slotsb, 0, Whh_bf, 0, gh_bf, 0, nullptr, 12800, 1536, 512, 1.0f);
        k_gru_pw<<<25600, 256, 0, stream>>>(gi_bf, gh_bf, b_ih, b_hh, slots, slotsb);
    }
    k_out<<<12800, 128, 0, stream>>>(updb, out);
}

// Round 4
// 1356.759 us; speedup vs baseline: 1.0918x; 1.0671x over previous
//
#include <hip/hip_runtime.h>
#include <math.h>

typedef __attribute__((ext_vector_type(4))) float f32x4;
typedef __attribute__((ext_vector_type(8))) short s16x8;

__device__ __forceinline__ unsigned rotl32(unsigned x, int r) {
    return (x << r) | (x >> (32 - r));
}
__device__ __forceinline__ unsigned short f2bf(float x) {
    unsigned u = __float_as_uint(x);
    unsigned r = (u + 0x7FFFu + ((u >> 16) & 1u)) >> 16;   // RNE
    return (unsigned short)r;
}
__device__ __forceinline__ float b2f(unsigned short b) {
    return __uint_as_float((unsigned)b << 16);
}
__device__ __forceinline__ void async16(const unsigned short* g, unsigned short* l) {
    __builtin_amdgcn_global_load_lds(
        (const __attribute__((address_space(1))) void*)g,
        (__attribute__((address_space(3))) void*)l, 16, 0, 0);
}

// XLA f32 erfinv (Giles polynomial)
__device__ __forceinline__ float bits_to_normal(unsigned bits) {
    float f = __uint_as_float((bits >> 9) | 0x3F800000u) - 1.0f;
    const float lo = -0.99999994f;
    float u = f * 2.0f + lo;
    u = fmaxf(lo, u);
    float w = -log1pf(-u * u);
    float p;
    if (w < 5.0f) {
        w -= 2.5f;
        p = 2.81022636e-08f;
        p = fmaf(p, w, 3.43273939e-07f);
        p = fmaf(p, w, -3.5233877e-06f);
        p = fmaf(p, w, -4.39150654e-06f);
        p = fmaf(p, w, 0.00021858087f);
        p = fmaf(p, w, -0.00125372503f);
        p = fmaf(p, w, -0.00417768164f);
        p = fmaf(p, w, 0.246640727f);
        p = fmaf(p, w, 1.50140941f);
    } else {
        w = sqrtf(w) - 3.0f;
        p = -0.000200214257f;
        p = fmaf(p, w, 0.000100950558f);
        p = fmaf(p, w, 0.00134934322f);
        p = fmaf(p, w, -0.00367342844f);
        p = fmaf(p, w, 0.00573950773f);
        p = fmaf(p, w, -0.0076224613f);
        p = fmaf(p, w, 0.00943887047f);
        p = fmaf(p, w, 1.00167406f);
        p = fmaf(p, w, 2.83297682f);
    }
    return 1.41421356237f * (p * u);
}

// slots = mu + |sigma| * threefry_normal(key=(0,1)), partitionable scheme.
__global__ __launch_bounds__(256)
void k_init_slots(const float* __restrict__ mu, const float* __restrict__ sigma,
                  float* __restrict__ slots, unsigned short* __restrict__ slotsb) {
    unsigned e = blockIdx.x * 256u + threadIdx.x;
    const unsigned ks0 = 0u, ks1 = 1u, ks2 = 0x1BD11BDBu;
    unsigned x0 = 0u + ks0;
    unsigned x1 = e + ks1;
#define TF_RND(r) { x0 += x1; x1 = rotl32(x1, r); x1 ^= x0; }
    TF_RND(13) TF_RND(15) TF_RND(26) TF_RND(6)   x0 += ks1; x1 += ks2 + 1u;
    TF_RND(17) TF_RND(29) TF_RND(16) TF_RND(24)  x0 += ks2; x1 += ks0 + 2u;
    TF_RND(13) TF_RND(15) TF_RND(26) TF_RND(6)   x0 += ks0; x1 += ks1 + 3u;
    TF_RND(17) TF_RND(29) TF_RND(16) TF_RND(24)  x0 += ks1; x1 += ks2 + 4u;
    TF_RND(13) TF_RND(15) TF_RND(26) TF_RND(6)   x0 += ks2; x1 += ks0 + 5u;
#undef TF_RND
    unsigned bits = x0 ^ x1;
    int d0 = (int)(e & 511u);
    float v = mu[d0] + fabsf(sigma[d0]) * bits_to_normal(bits);
    slots[e] = v;
    slotsb[e] = f2bf(v);
}

// flat f32 -> bf16 cast, 4 elems/thread
__global__ __launch_bounds__(256)
void k_cast(const float* __restrict__ s, unsigned short* __restrict__ d, int n4) {
    int i = blockIdx.x * 256 + threadIdx.x;
    if (i < n4) {
        float4 v = ((const float4*)s)[i];
        ((ushort4*)d)[i] = make_ushort4(f2bf(v.x), f2bf(v.y), f2bf(v.z), f2bf(v.w));
    }
}

// x [128][1024][512] f32 (b,j,d) -> xT [128][512][1024] bf16 (b,d,j)
__global__ __launch_bounds__(256)
void k_transpose_cast(const float* __restrict__ x, unsigned short* __restrict__ xT) {
    __shared__ float t[32][33];
    int b = blockIdx.z;
    int j0 = blockIdx.x * 32;
    int d0 = blockIdx.y * 32;
    int tx = threadIdx.x & 31, ty = threadIdx.x >> 5;   // ty 0..7
    const float* xp = x + ((long long)b * 1024 + j0) * 512 + d0;
#pragma unroll
    for (int q = 0; q < 4; q++) {
        int j = ty + q * 8;
        t[j][tx] = xp[(long long)j * 512 + tx];
    }
    __syncthreads();
    unsigned short* op = xT + ((long long)b * 512 + d0) * 1024 + j0;
#pragma unroll
    for (int q = 0; q < 4; q++) {
        int d = ty + q * 8;
        op[(long long)d * 1024 + tx] = f2bf(t[tx][d]);
    }
}

// W [512x512] f32 -> WT [512x512] bf16, WT[a,b] = W[b,a]
__global__ __launch_bounds__(256)
void k_transpose_cast_512(const float* __restrict__ W, unsigned short* __restrict__ WT) {
    __shared__ float t[32][33];
    int r0 = blockIdx.y * 32;
    int c0 = blockIdx.x * 32;
    int tx = threadIdx.x & 31, ty = threadIdx.x >> 5;   // ty 0..7
#pragma unroll
    for (int q = 0; q < 4; q++) {
        int i = ty + q * 8;
        t[i][tx] = W[(r0 + i) * 512 + c0 + tx];
    }
    __syncthreads();
#pragma unroll
    for (int q = 0; q < 4; q++) {
        int i = ty + q * 8;
        WT[(c0 + i) * 512 + r0 + tx] = f2bf(t[tx][i]);
    }
}

// c[d] = sum_e bq[e] * Wk[e*512 + d]   (folded q-bias through Wk)
__global__ __launch_bounds__(64)
void k_bias_fold(const float* __restrict__ bq, const float* __restrict__ Wk,
                 float* __restrict__ c) {
    int d = blockIdx.x * 64 + threadIdx.x;
    float s = 0.0f;
    for (int e = 0; e < 512; e++) s += bq[e] * Wk[e * 512 + d];
    c[d] = s;
}

// C[m,n] = bf16( alpha * sum_k A[m,k]*B[n,k] (+ bias[n]) )
// A: f32 (A_F32, staged w/ in-kernel cast) or bf16 (global_load_lds x16B).
// B: bf16 [N x K] row-major (NT). 128x128 tile, BK=32, 4 waves, 16x16x32 MFMA.
// 2-PHASE PIPELINE: LDS double-buffered; loads for K-step t+1 issued before
// the MFMA phase of step t, waited at the single end-of-step __syncthreads.
template<bool A_F32, bool HAS_BIAS, bool XSWZ = false>
__global__ __launch_bounds__(256)
void k_mfma_nt(const void* __restrict__ Araw, long long sA,
               const unsigned short* __restrict__ B, long long sB,
               unsigned short* __restrict__ C, long long sC,
               const float* __restrict__ bias,
               int M, int N, int K, float alpha) {
    __shared__ __align__(16) unsigned short As[2][128 * 32];
    __shared__ __align__(16) unsigned short Bs[2][128 * 32];
    const int tid = threadIdx.x;
    const unsigned short* Ab = (const unsigned short*)Araw + (long long)blockIdx.z * sA;
    const float* Af = (const float*)Araw + (long long)blockIdx.z * sA;
    const unsigned short* Bb = B + (long long)blockIdx.z * sB;
    C += (long long)blockIdx.z * sC;

    int nb, mb;
    if (XSWZ) {
        unsigned L = blockIdx.x;
        unsigned x = L & 7u;
        unsigned j = L >> 3u;
        unsigned panels = gridDim.x >> 5u;
        mb = (int)(x * panels + (j >> 2u));
        nb = (int)(j & 3u);
    } else {
        nb = blockIdx.x;
        mb = blockIdx.y;
    }
    const int n0 = nb * 128;
    const int m0 = mb * 128;

    const int lane = tid & 63;
    const int wave = tid >> 6;
    const int wm = (wave >> 1) * 64;
    const int wn = (wave & 1) * 64;
    const int lrow = lane & 15;
    const int lquad = lane >> 4;

    f32x4 acc[4][4];
#pragma unroll
    for (int i = 0; i < 4; i++)
#pragma unroll
        for (int j = 0; j < 4; j++) acc[i][j] = (f32x4)0.0f;

    // staging coords
    const int arow_s = tid >> 1;                 // A_F32: row, 2 thr/row
    const int akh_s = (tid & 1) * 16;            // A_F32: k sub-offset
    int arowg_s = m0 + arow_s; if (arowg_s >= M) arowg_s = M - 1;

    // async-staging coords (shared by A-bf16 and B paths)
    const int c0_row = tid >> 2;                 // p=0 row
    const int c0_kc = (tid & 3) * 8;
    const int ldsoff0 = (tid & ~63) * 8;         // p=0 LDS elem offset (wave-linear)
    const int ldsoff1 = (256 + (tid & ~63)) * 8; // p=1

    float4 f0, f1, f2, f3;                       // A_F32 prefetch regs

    auto loadAf32 = [&](int k0) {
        const float* ap = Af + (long long)arowg_s * K + k0 + akh_s;
        f0 = *(const float4*)(ap);
        f1 = *(const float4*)(ap + 4);
        f2 = *(const float4*)(ap + 8);
        f3 = *(const float4*)(ap + 12);
    };
    auto castA = [&](unsigned short* dst) {
        s16x8 p0, p1;
        p0[0] = (short)f2bf(f0.x); p0[1] = (short)f2bf(f0.y);
        p0[2] = (short)f2bf(f0.z); p0[3] = (short)f2bf(f0.w);
        p0[4] = (short)f2bf(f1.x); p0[5] = (short)f2bf(f1.y);
        p0[6] = (short)f2bf(f1.z); p0[7] = (short)f2bf(f1.w);
        p1[0] = (short)f2bf(f2.x); p1[1] = (short)f2bf(f2.y);
        p1[2] = (short)f2bf(f2.z); p1[3] = (short)f2bf(f2.w);
        p1[4] = (short)f2bf(f3.x); p1[5] = (short)f2bf(f3.y);
        p1[6] = (short)f2bf(f3.z); p1[7] = (short)f2bf(f3.w);
        *(s16x8*)&dst[arow_s * 32 + akh_s] = p0;
        *(s16x8*)&dst[arow_s * 32 + akh_s + 8] = p1;
    };
    auto stageAasync = [&](int k0, unsigned short* dst) {
        int r0 = m0 + c0_row;       if (r0 >= M) r0 = M - 1;
        int r1 = m0 + 64 + c0_row;  if (r1 >= M) r1 = M - 1;
        async16(Ab + (long long)r0 * K + k0 + c0_kc, &dst[ldsoff0]);
        async16(Ab + (long long)r1 * K + k0 + c0_kc, &dst[ldsoff1]);
    };
    auto stageB = [&](int k0, unsigned short* dst) {
        async16(Bb + (long long)(n0 + c0_row) * K + k0 + c0_kc, &dst[ldsoff0]);
        async16(Bb + (long long)(n0 + 64 + c0_row) * K + k0 + c0_kc, &dst[ldsoff1]);
    };

    const int nt = K >> 5;   // K-steps of 32

    // ---- prologue: stage t=0 into buffer 0 ----
    if (A_F32) {
        loadAf32(0);
        stageB(0, Bs[0]);
        castA(As[0]);
    } else {
        stageAasync(0, As[0]);
        stageB(0, Bs[0]);
    }
    __syncthreads();   // drains vmcnt (async) + lgkmcnt (castA writes)

    int cur = 0;
    for (int t = 0; t < nt; ++t) {
        const int nxt = cur ^ 1;
        const bool more = (t + 1 < nt);
        // ---- issue loads for t+1 (land during MFMA phase) ----
        if (more) {
            const int k1 = (t + 1) << 5;
            if (A_F32) {
                loadAf32(k1);              // f32 -> regs, consumed after MFMA
            } else {
                stageAasync(k1, As[nxt]);
            }
            stageB(k1, Bs[nxt]);
        }
        // ---- compute phase on buffer cur ----
        const unsigned short* Asc = As[cur];
        const unsigned short* Bsc = Bs[cur];
        s16x8 afr[4], bfr[4];
#pragma unroll
        for (int i = 0; i < 4; i++)
            afr[i] = *(const s16x8*)&Asc[(wm + i * 16 + lrow) * 32 + lquad * 8];
#pragma unroll
        for (int j = 0; j < 4; j++)
            bfr[j] = *(const s16x8*)&Bsc[(wn + j * 16 + lrow) * 32 + lquad * 8];
#pragma unroll
        for (int i = 0; i < 4; i++)
#pragma unroll
            for (int j = 0; j < 4; j++)
                acc[i][j] = __builtin_amdgcn_mfma_f32_16x16x32_bf16(
                    afr[i], bfr[j], acc[i][j], 0, 0, 0);
        // ---- finish staging t+1 (A_F32: cast regs -> LDS after MFMA) ----
        if (more && A_F32) castA(As[nxt]);
        __syncthreads();   // single per-step drain: vmcnt (async) + lgkmcnt
        cur = nxt;
    }

#pragma unroll
    for (int i = 0; i < 4; i++) {
#pragma unroll
        for (int r = 0; r < 4; r++) {
            int grow = m0 + wm + i * 16 + lquad * 4 + r;
            if (grow < M) {
#pragma unroll
                for (int j = 0; j < 4; j++) {
                    int gcol = n0 + wn + j * 16 + lrow;
                    float v = acc[i][j][r] * alpha;
                    if (HAS_BIAS) v += bias[gcol];
                    C[(long long)grow * N + gcol] = f2bf(v);
                }
            }
        }
    }
}

// in-place row softmax over 1024 bf16, one 256-thread block per row
__global__ __launch_bounds__(256)
void k_softmax_bf(unsigned short* __restrict__ attn) {
    __shared__ float red[8];
    unsigned short* p = attn + (long long)blockIdx.x * 1024;
    ushort4 v = ((const ushort4*)p)[threadIdx.x];
    float a0 = b2f(v.x), a1 = b2f(v.y), a2 = b2f(v.z), a3 = b2f(v.w);
    float mx = fmaxf(fmaxf(a0, a1), fmaxf(a2, a3));
#pragma unroll
    for (int off = 32; off; off >>= 1) mx = fmaxf(mx, __shfl_down(mx, off));
    int wid = threadIdx.x >> 6, lane = threadIdx.x & 63;
    if (lane == 0) red[wid] = mx;
    __syncthreads();
    mx = fmaxf(fmaxf(red[0], red[1]), fmaxf(red[2], red[3]));
    float e0 = expf(a0 - mx), e1 = expf(a1 - mx);
    float e2 = expf(a2 - mx), e3 = expf(a3 - mx);
    float s = (e0 + e1) + (e2 + e3);
#pragma unroll
    for (int off = 32; off; off >>= 1) s += __shfl_down(s, off);
    if (lane == 0) red[4 + wid] = s;
    __syncthreads();
    float inv = 1.0f / ((red[4] + red[5]) + (red[6] + red[7]));
    ((ushort4*)p)[threadIdx.x] =
        make_ushort4(f2bf(e0 * inv), f2bf(e1 * inv), f2bf(e2 * inv), f2bf(e3 * inv));
}

// GRU pointwise from bf16 gate pre-activations; slots updated in place (f32+bf16)
__global__ __launch_bounds__(256)
void k_gru_pw(const unsigned short* __restrict__ gi, const unsigned short* __restrict__ gh,
              const float* __restrict__ bih, const float* __restrict__ bhh,
              float* __restrict__ slots, unsigned short* __restrict__ slotsb) {
    long long idx = (long long)blockIdx.x * 256 + threadIdx.x;
    int m = (int)(idx >> 9);
    int c = (int)(idx & 511);
    const unsigned short* gim = gi + (long long)m * 1536;
    const unsigned short* ghm = gh + (long long)m * 1536;
    float r = 1.0f / (1.0f + expf(-(b2f(gim[c]) + b2f(ghm[c]) + bih[c] + bhh[c])));
    float z = 1.0f / (1.0f + expf(-(b2f(gim[512 + c]) + b2f(ghm[512 + c])
                                    + bih[512 + c] + bhh[512 + c])));
    float hn = b2f(ghm[1024 + c]) + bhh[1024 + c];
    float nn = tanhf(b2f(gim[1024 + c]) + bih[1024 + c] + r * hn);
    float hp = slots[idx];
    float h = (1.0f - z) * nn + z * hp;
    slots[idx] = h;
    slotsb[idx] = f2bf(h);
}

// out[row] = sum_d updb[row, d];  out[12800] = 1/1024 (slot_loss, exact)
__global__ __launch_bounds__(128)
void k_out(const unsigned short* __restrict__ updb, float* __restrict__ out) {
    __shared__ float r2[2];
    const unsigned short* p = updb + (long long)blockIdx.x * 512;
    ushort4 v = ((const ushort4*)p)[threadIdx.x];
    float s = (b2f(v.x) + b2f(v.y)) + (b2f(v.z) + b2f(v.w));
#pragma unroll
    for (int off = 32; off; off >>= 1) s += __shfl_down(s, off);
    if ((threadIdx.x & 63) == 0) r2[threadIdx.x >> 6] = s;
    __syncthreads();
    if (threadIdx.x == 0) {
        out[blockIdx.x] = r2[0] + r2[1];
        if (blockIdx.x == 0) out[12800] = 0.0009765625f;
    }
}

extern "C" void kernel_launch(void* const* d_in, const int* in_sizes, int n_in,
                              void* d_out, int out_size, void* d_ws, size_t ws_size,
                              hipStream_t stream) {
    const float* inputs   = (const float*)d_in[0];
    const float* inputs_x = (const float*)d_in[1];
    const float* mu       = (const float*)d_in[2];
    const float* sigma    = (const float*)d_in[3];
    const float* to_q_w   = (const float*)d_in[4];
    const float* to_q_b   = (const float*)d_in[5];
    const float* to_k_w   = (const float*)d_in[6];
    const float* to_k_b   = (const float*)d_in[7];
    const float* w_ih     = (const float*)d_in[8];
    const float* w_hh     = (const float*)d_in[9];
    const float* b_ih     = (const float*)d_in[10];
    const float* b_hh     = (const float*)d_in[11];
    float* out = (float*)d_out;

    // ws layout (bytes), total ~404.2 MB (< 425.7 MB proven available):
    char* base = (char*)d_ws;
    unsigned short* inp_bf = (unsigned short*)(base);                 // 134,217,728 (inputs, bf16, [b][j][d])
    unsigned short* xT     = (unsigned short*)(base + 134217728ll);   // 134,217,728 (inputs_x^T bf16)
    float*          slots  = (float*)        (base + 268435456ll);    //  26,214,400
    unsigned short* slotsb = (unsigned short*)(base + 294649856ll);   //  13,107,200
    unsigned short* updb   = (unsigned short*)(base + 307757056ll);   //  13,107,200
    char* regionA          = base + 320864256ll;                      //  39,321,600 (qk | gi)
    char* regionB          = base + 360185856ll;                      //  39,321,600 (attn | gh)
    unsigned short* WkT_bf = (unsigned short*)(base + 399507456ll);   //     524,288 (to_k_w^T bf16)
    unsigned short* WqT_bf = (unsigned short*)(base + 400031744ll);   //     524,288 (to_q_w^T bf16)
    unsigned short* Wih_bf = (unsigned short*)(base + 400556032ll);   //   1,572,864
    unsigned short* Whh_bf = (unsigned short*)(base + 402128896ll);   //   1,572,864
    unsigned short* Gt_bf  = (unsigned short*)(base + 403701760ll);   //     524,288 (Wk^T@Wq fused weight)
    float*          c_fold = (float*)        (base + 404226048ll);    //       2,048 (bq@Wk)
    unsigned short* qk_bf  = (unsigned short*)regionA;
    unsigned short* gi_bf  = (unsigned short*)regionA;
    unsigned short* attnb  = (unsigned short*)regionB;
    unsigned short* gh_bf  = (unsigned short*)regionB;

    // ---- prologue ----
    k_init_slots<<<25600, 256, 0, stream>>>(mu, sigma, slots, slotsb);
    k_cast<<<768, 256, 0, stream>>>(w_ih, Wih_bf, 196608);
    k_cast<<<768, 256, 0, stream>>>(w_hh, Whh_bf, 196608);
    // inputs f32 -> bf16 (replaces the K-projection GEMM's A-read; dots reads this as B)
    k_cast<<<65536, 256, 0, stream>>>(inputs, inp_bf, 16777216);
    k_transpose_cast<<<dim3(32, 16, 128), 256, 0, stream>>>(inputs_x, xT);
    // fused q/k weight: Gt[d,e] = sum_d' Wk[d',d]*Wq[d',e]  (= (q@Wk) weight)
    k_transpose_cast_512<<<dim3(16, 16), 256, 0, stream>>>(to_k_w, WkT_bf);
    k_transpose_cast_512<<<dim3(16, 16), 256, 0, stream>>>(to_q_w, WqT_bf);
    k_bias_fold<<<8, 64, 0, stream>>>(to_q_b, to_k_w, c_fold);
    k_mfma_nt<false, false><<<dim3(4, 4, 1), 256, 0, stream>>>(
        WkT_bf, 0, WqT_bf, 0, Gt_bf, 0, nullptr, 512, 512, 512, 1.0f);
    // NOTE: k = inputs@Wk^T is never materialized. dots = (q@Wk) @ inputs^T;
    // the bk term is a per-row constant in dots -> softmax-invariant (dropped).

    const float scale = 0.044194173824159216f;   // 512^-0.5
    for (int it = 0; it < 3; ++it) {
        // qk = slots @ Gt^T + c_fold : [12800 x 512]  (same cost as old q-proj)
        k_mfma_nt<false, true><<<dim3(4, 100, 1), 256, 0, stream>>>(
            slotsb, 0, Gt_bf, 0, qk_bf, 0, c_fold, 12800, 512, 512, 1.0f);
        // dots = scale * qk @ inputs^T : 128 x [100 x 1024]
        k_mfma_nt<false, false><<<dim3(8, 1, 128), 256, 0, stream>>>(
            qk_bf, 51200, inp_bf, 524288, attnb, 102400, nullptr, 100, 1024, 512, scale);
        k_softmax_bf<<<12800, 256, 0, stream>>>(attnb);
        // updates = (attn @ x) / 512 : 128 x [100 x 512] (x pre-transposed)
        k_mfma_nt<false, false><<<dim3(4, 1, 128), 256, 0, stream>>>(
            attnb, 102400, xT, 524288, updb, 51200, nullptr, 100, 512, 1024, 0.001953125f);
        // gi = upd @ Wih.T ; gh = slots @ Whh.T : [12800 x 1536]
        k_mfma_nt<false, false><<<dim3(12, 100, 1), 256, 0, stream>>>(
            updb, 0, Wih_bf, 0, gi_bf, 0, nullptr, 12800, 1536, 512, 1.0f);
        k_mfma_nt<false, false><<<dim3(12, 100, 1), 256, 0, stream>>>(
            slotsb, 0, Whh_bf, 0, gh_bf, 0, nullptr, 12800, 1536, 512, 1.0f);
        k_gru_pw<<<25600, 256, 0, stream>>>(gi_bf, gh_bf, b_ih, b_hh, slots, slotsb);
    }
    k_out<<<12800, 128, 0, stream>>>(updb, out);
}